// Round 1
// baseline (447.181 us; speedup 1.0000x reference)
//
#include <hip/hip_runtime.h>

// Problem: B=16, N=2048, D=64 scaled-dot-product attention, fp32 in/out.
// Outputs concatenated: out [B,N,D] then attn_weights [B,N,N].
#define B_  16
#define N_  2048
#define D_  64
#define KT  64            // key tile
#define NTILES (N_ / KT)  // 32
// scale * log2(e) = (1/8) * 1.4426950408889634
#define SCALE_LOG2 0.18033688011112042f

typedef __attribute__((ext_vector_type(8))) short  frag8;   // 8 bf16 (4 VGPRs)
typedef __attribute__((ext_vector_type(4))) float  floatx4; // 4 fp32 acc

__device__ __forceinline__ unsigned short f2bf(float f) {
    unsigned int u = __builtin_bit_cast(unsigned int, f);
    u += 0x7fffu + ((u >> 16) & 1u);   // round-to-nearest-even
    return (unsigned short)(u >> 16);
}

__global__ __launch_bounds__(256) void attn_fused(
    const float* __restrict__ Q, const float* __restrict__ K,
    const float* __restrict__ V, float* __restrict__ out,
    float* __restrict__ attn)
{
    // +8 ushort pad (stride 72 = 144B, 16B-aligned rows, breaks bank conflicts)
    __shared__ unsigned short Qs[64][72];
    __shared__ unsigned short Ks[64][72];
    __shared__ unsigned short Vt[64][72];   // Vt[dim][key] (transposed)
    __shared__ unsigned short Ps[4][16][72]; // per-wave P staging (C->A layout)

    const int qtile = blockIdx.x;   // 0..31
    const int b     = blockIdx.y;   // 0..15
    const int qbase = qtile * 64;
    const int tid   = threadIdx.x;
    const int w     = tid >> 6;     // wave 0..3 -> Q rows [16w,16w+16)
    const int lane  = tid & 63;
    const int lm    = lane & 15;
    const int quad  = lane >> 4;
    const int q8    = quad * 8;

    // ---- stage Q tile fp32 -> bf16 ----
    {
        const int row = tid >> 2;
        const int c0  = (tid & 3) * 16;
        const float4* src = (const float4*)(Q + ((size_t)(b*N_ + qbase + row))*D_ + c0);
        #pragma unroll
        for (int i = 0; i < 4; ++i) {
            float4 f = src[i];
            ushort4 u; u.x=f2bf(f.x); u.y=f2bf(f.y); u.z=f2bf(f.z); u.w=f2bf(f.w);
            *(ushort4*)&Qs[row][c0 + i*4] = u;
        }
    }
    __syncthreads();
    // A-frags for this wave's 16 Q rows: A[m=lane&15][k=quad*8+j (+32)]
    const frag8 aq0 = *(const frag8*)&Qs[w*16 + lm][q8];
    const frag8 aq1 = *(const frag8*)&Qs[w*16 + lm][32 + q8];

    float m[4], l[4];
    #pragma unroll
    for (int r = 0; r < 4; ++r) { m[r] = -1e30f; l[r] = 0.0f; }

    // ================= sweep 1: row max & exp-sum (online) =================
    for (int t = 0; t < NTILES; ++t) {
        __syncthreads();
        {
            const int row = tid >> 2;
            const int c0  = (tid & 3) * 16;
            const float4* src = (const float4*)(K + ((size_t)(b*N_ + t*KT + row))*D_ + c0);
            #pragma unroll
            for (int i = 0; i < 4; ++i) {
                float4 f = src[i];
                ushort4 u; u.x=f2bf(f.x); u.y=f2bf(f.y); u.z=f2bf(f.z); u.w=f2bf(f.w);
                *(ushort4*)&Ks[row][c0 + i*4] = u;
            }
        }
        __syncthreads();

        floatx4 acc[4];
        #pragma unroll
        for (int ns = 0; ns < 4; ++ns) {
            frag8 b0 = *(const frag8*)&Ks[ns*16 + lm][q8];
            frag8 b1 = *(const frag8*)&Ks[ns*16 + lm][32 + q8];
            floatx4 a = {0.f, 0.f, 0.f, 0.f};
            a = __builtin_amdgcn_mfma_f32_16x16x32_bf16(aq0, b0, a, 0, 0, 0);
            a = __builtin_amdgcn_mfma_f32_16x16x32_bf16(aq1, b1, a, 0, 0, 0);
            acc[ns] = a;
        }
        // C-layout: element (row = quad*4 + r, col = lane&15) per 16-col subtile ns
        #pragma unroll
        for (int r = 0; r < 4; ++r) {
            float tm = fmaxf(fmaxf(acc[0][r], acc[1][r]), fmaxf(acc[2][r], acc[3][r]));
            #pragma unroll
            for (int off = 1; off < 16; off <<= 1)
                tm = fmaxf(tm, __shfl_xor(tm, off, 64));
            float mn = fmaxf(m[r], tm * SCALE_LOG2);
            float c  = exp2f(m[r] - mn);
            float s  = 0.0f;
            #pragma unroll
            for (int ns = 0; ns < 4; ++ns)
                s += exp2f(acc[ns][r] * SCALE_LOG2 - mn);
            #pragma unroll
            for (int off = 1; off < 16; off <<= 1)
                s += __shfl_xor(s, off, 64);
            l[r] = l[r] * c + s;
            m[r] = mn;
        }
    }

    float invl[4];
    #pragma unroll
    for (int r = 0; r < 4; ++r) invl[r] = 1.0f / l[r];

    floatx4 oacc[4];
    #pragma unroll
    for (int ns = 0; ns < 4; ++ns) oacc[ns] = (floatx4){0.f, 0.f, 0.f, 0.f};

    // ========== sweep 2: recompute S, write attn, accumulate O=PV ==========
    for (int t = 0; t < NTILES; ++t) {
        __syncthreads();
        {
            const int row = tid >> 2;
            const int c0  = (tid & 3) * 16;
            const float4* srcK = (const float4*)(K + ((size_t)(b*N_ + t*KT + row))*D_ + c0);
            const float4* srcV = (const float4*)(V + ((size_t)(b*N_ + t*KT + row))*D_ + c0);
            #pragma unroll
            for (int i = 0; i < 4; ++i) {
                float4 f = srcK[i];
                ushort4 u; u.x=f2bf(f.x); u.y=f2bf(f.y); u.z=f2bf(f.z); u.w=f2bf(f.w);
                *(ushort4*)&Ks[row][c0 + i*4] = u;
            }
            #pragma unroll
            for (int i = 0; i < 4; ++i) {  // V transposed: Vt[dim][key]
                float4 f = srcV[i];
                Vt[c0 + i*4 + 0][row] = f2bf(f.x);
                Vt[c0 + i*4 + 1][row] = f2bf(f.y);
                Vt[c0 + i*4 + 2][row] = f2bf(f.z);
                Vt[c0 + i*4 + 3][row] = f2bf(f.w);
            }
        }
        __syncthreads();

        floatx4 acc[4];
        #pragma unroll
        for (int ns = 0; ns < 4; ++ns) {
            frag8 b0 = *(const frag8*)&Ks[ns*16 + lm][q8];
            frag8 b1 = *(const frag8*)&Ks[ns*16 + lm][32 + q8];
            floatx4 a = {0.f, 0.f, 0.f, 0.f};
            a = __builtin_amdgcn_mfma_f32_16x16x32_bf16(aq0, b0, a, 0, 0, 0);
            a = __builtin_amdgcn_mfma_f32_16x16x32_bf16(aq1, b1, a, 0, 0, 0);
            acc[ns] = a;
        }

        // normalized attention weights -> global (64B line per quad) + LDS (bf16)
        #pragma unroll
        for (int ns = 0; ns < 4; ++ns) {
            #pragma unroll
            for (int r = 0; r < 4; ++r) {
                float p = exp2f(acc[ns][r] * SCALE_LOG2 - m[r]) * invl[r];
                attn[((size_t)(b*N_ + qbase + w*16 + quad*4 + r))*N_ + t*KT + ns*16 + lm] = p;
                Ps[w][quad*4 + r][ns*16 + lm] = f2bf(p);
            }
        }

        // P: C-layout -> A-layout via per-wave LDS round-trip (in-wave, no barrier)
        frag8 pa0 = *(const frag8*)&Ps[w][lm][q8];
        frag8 pa1 = *(const frag8*)&Ps[w][lm][32 + q8];
        #pragma unroll
        for (int ns = 0; ns < 4; ++ns) {
            frag8 v0 = *(const frag8*)&Vt[ns*16 + lm][q8];       // B[k=key][n=dim]
            frag8 v1 = *(const frag8*)&Vt[ns*16 + lm][32 + q8];
            oacc[ns] = __builtin_amdgcn_mfma_f32_16x16x32_bf16(pa0, v0, oacc[ns], 0, 0, 0);
            oacc[ns] = __builtin_amdgcn_mfma_f32_16x16x32_bf16(pa1, v1, oacc[ns], 0, 0, 0);
        }
    }

    // ---- write O [B,N,D] ----
    #pragma unroll
    for (int ns = 0; ns < 4; ++ns)
        #pragma unroll
        for (int r = 0; r < 4; ++r)
            out[((size_t)(b*N_ + qbase + w*16 + quad*4 + r))*D_ + ns*16 + lm] = oacc[ns][r];
}

extern "C" void kernel_launch(void* const* d_in, const int* in_sizes, int n_in,
                              void* d_out, int out_size, void* d_ws, size_t ws_size,
                              hipStream_t stream) {
    const float* Q = (const float*)d_in[0];
    const float* K = (const float*)d_in[1];
    const float* V = (const float*)d_in[2];
    float* out  = (float*)d_out;
    float* attn = out + (size_t)B_ * N_ * D_;   // tuple order: out, attn_weights
    dim3 grid(NTILES, B_);   // 32 x 16 = 512 blocks
    attn_fused<<<grid, 256, 0, stream>>>(Q, K, V, out, attn);
}